// Round 1
// baseline (162.743 us; speedup 1.0000x reference)
//
#include <hip/hip_runtime.h>
#include <cstdint>
#include <cstddef>

#define NUSERS 100000
#define BB 16384

static __device__ __forceinline__ float readlane_f(float v, int l) {
    return __uint_as_float(__builtin_amdgcn_readlane(__float_as_uint(v), l));
}

// ---------------- K0: per-user attention score Q[u] = tanh(f[u]@wg1+bg1)@wg2 + bg2
__global__ __launch_bounds__(256) void k0_scores(
    const float* __restrict__ features, const float* __restrict__ wg1,
    const float* __restrict__ bg1, const float* __restrict__ wg2,
    const float* __restrict__ bg2, float* __restrict__ Q)
{
    __shared__ float frow[16 * 68];   // 16 user rows, padded
    __shared__ float wg1t[16 * 68];   // wg1 transposed [k][d], padded
    const int tid = threadIdx.x;
    const int blk = blockIdx.x;
    const float* fbase = features + (size_t)blk * 16 * 64;
    for (int i = tid; i < 1024; i += 256) {
        frow[(i >> 6) * 68 + (i & 63)] = fbase[i];          // user rows are contiguous
        wg1t[(i & 15) * 68 + (i >> 4)] = wg1[i];            // [d][k] -> [k][d]
    }
    __syncthreads();
    const int k = tid & 15, ul = tid >> 4;
    float x = bg1[k];
    #pragma unroll
    for (int d4 = 0; d4 < 16; ++d4) {
        const float4 f = *(const float4*)&frow[ul * 68 + d4 * 4];
        const float4 w = *(const float4*)&wg1t[k * 68 + d4 * 4];
        x += f.x * w.x + f.y * w.y + f.z * w.z + f.w * w.w;
    }
    float t = tanhf(x) * wg2[k];
    t += __shfl_xor(t, 1);
    t += __shfl_xor(t, 2);
    t += __shfl_xor(t, 4);
    t += __shfl_xor(t, 8);
    if (k == 0) Q[blk * 16 + ul] = t + bg2[0];
}

// ---------------- K1: fused attention-pool + masked means -> combined[B][128]
__global__ __launch_bounds__(256) void k1_fuse(
    const int* __restrict__ nodes, const int* __restrict__ hist_u,
    const int* __restrict__ hist_r, const int* __restrict__ hist_m,
    const int* __restrict__ soc_a, const int* __restrict__ soc_m,
    const float* __restrict__ features, const float* __restrict__ r_embed,
    const float* __restrict__ Q, float* __restrict__ comb, int nwaves)
{
    __shared__ float remb[5 * 64];
    const int tid = threadIdx.x;
    for (int i = tid; i < 320; i += 256) remb[i] = r_embed[i];
    __syncthreads();
    const int lane = tid & 63;
    const int wid = __builtin_amdgcn_readfirstlane((int)(blockIdx.x * 4 + (tid >> 6)));

    for (int e = wid; e < BB; e += nwaves) {
        // ---- group attention (Q already holds per-user logits) ----
        int nd = 0;
        if (lane < 8) nd = nodes[e * 8 + lane];
        float m[8];
        #pragma unroll
        for (int g = 0; g < 8; ++g) {
            int idx = __builtin_amdgcn_readlane(nd, g);
            m[g] = features[idx * 64 + lane];
        }
        float sc = (lane < 8) ? Q[nd] : -1e30f;
        float mx = sc;
        mx = fmaxf(mx, __shfl_xor(mx, 1));
        mx = fmaxf(mx, __shfl_xor(mx, 2));
        mx = fmaxf(mx, __shfl_xor(mx, 4));
        float ex = __expf(sc - mx);
        float sm = ex;
        sm += __shfl_xor(sm, 1);
        sm += __shfl_xor(sm, 2);
        sm += __shfl_xor(sm, 4);
        float al = ex / sm;          // valid on lanes 0..7
        float sf = 0.f;
        #pragma unroll
        for (int g = 0; g < 8; ++g)
            sf += readlane_f(al, g) * m[g];

        // ---- history masked mean (skip inactive rows via ballot bits) ----
        int hu_p = 0, hr_p = 0, hm_p = 0;
        if (lane < 50) {
            hu_p = hist_u[e * 50 + lane];
            hr_p = hist_r[e * 50 + lane];
            hm_p = hist_m[e * 50 + lane];
        }
        uint64_t hb = __ballot(hm_p != 0);   // lanes >= 50 contribute 0
        const int hc = (int)__popcll(hb);
        float ha = 0.f;
        while (hb) {
            int l = __builtin_amdgcn_readfirstlane((int)__builtin_ctzll(hb));
            hb &= hb - 1;
            int u = __builtin_amdgcn_readlane(hu_p, l);
            int r = __builtin_amdgcn_readlane(hr_p, l);
            ha += features[u * 64 + lane] + remb[r * 64 + lane];
        }
        float hmean = ha / (float)max(hc, 1);

        // ---- social masked mean ----
        int sa_p = 0, sm_p = 0;
        if (lane < 32) {
            sa_p = soc_a[e * 32 + lane];
            sm_p = soc_m[e * 32 + lane];
        }
        uint64_t sb = __ballot(sm_p != 0);
        const int scn = (int)__popcll(sb);
        float sacc = 0.f;
        while (sb) {
            int l = __builtin_amdgcn_readfirstlane((int)__builtin_ctzll(sb));
            sb &= sb - 1;
            int u = __builtin_amdgcn_readlane(sa_p, l);
            sacc += features[u * 64 + lane];
        }
        float smean = sacc / (float)max(scn, 1);

        comb[(size_t)e * 128 + lane] = sf;
        comb[(size_t)e * 128 + 64 + lane] = 0.5f * (hmean + smean);
    }
}

// ---------------- K2: out = relu(comb[B][128] @ w1[128][64] + b1)
__global__ __launch_bounds__(256) void k2_gemm(
    const float* __restrict__ comb, const float* __restrict__ w1,
    const float* __restrict__ b1, float* __restrict__ out)
{
    __shared__ float w1s[128 * 64];
    __shared__ float4 ct4[32 * 32];   // 32 rows x 128 floats
    const int tid = threadIdx.x;
    const float4* w14 = (const float4*)w1;
    float4* w1s4 = (float4*)w1s;
    for (int i = tid; i < 2048; i += 256) w1s4[i] = w14[i];
    const float4* c4 = (const float4*)(comb + (size_t)blockIdx.x * 32 * 128);
    for (int i = tid; i < 1024; i += 256) ct4[i] = c4[i];
    __syncthreads();

    const int n = tid & 63, wv = tid >> 6;
    const float bv = b1[n];
    float acc[8] = {bv, bv, bv, bv, bv, bv, bv, bv};
    #pragma unroll
    for (int k4 = 0; k4 < 32; ++k4) {
        float w0 = w1s[(k4 * 4 + 0) * 64 + n];
        float w1v = w1s[(k4 * 4 + 1) * 64 + n];
        float w2v = w1s[(k4 * 4 + 2) * 64 + n];
        float w3v = w1s[(k4 * 4 + 3) * 64 + n];
        #pragma unroll
        for (int i = 0; i < 8; ++i) {
            float4 cv = ct4[(wv * 8 + i) * 32 + k4];
            acc[i] += cv.x * w0 + cv.y * w1v + cv.z * w2v + cv.w * w3v;
        }
    }
    const int row0 = blockIdx.x * 32 + wv * 8;
    #pragma unroll
    for (int i = 0; i < 8; ++i)
        out[(size_t)(row0 + i) * 64 + n] = fmaxf(acc[i], 0.f);
}

extern "C" void kernel_launch(void* const* d_in, const int* in_sizes, int n_in,
                              void* d_out, int out_size, void* d_ws, size_t ws_size,
                              hipStream_t stream)
{
    const int*   nodes    = (const int*)d_in[0];
    const int*   hu       = (const int*)d_in[1];
    const int*   hr       = (const int*)d_in[2];
    const int*   hm       = (const int*)d_in[3];
    const int*   sa       = (const int*)d_in[4];
    const int*   smk      = (const int*)d_in[5];
    const float* features = (const float*)d_in[6];
    const float* r_embed  = (const float*)d_in[7];
    const float* wg1      = (const float*)d_in[8];
    const float* bg1      = (const float*)d_in[9];
    const float* wg2      = (const float*)d_in[10];
    const float* bg2      = (const float*)d_in[11];
    const float* w1       = (const float*)d_in[12];
    const float* b1       = (const float*)d_in[13];
    float* out = (float*)d_out;

    float* Q    = (float*)d_ws;          // 100000 floats
    float* comb = Q + 131072;            // 16384*128 floats = 8 MB

    k0_scores<<<NUSERS / 16, 256, 0, stream>>>(features, wg1, bg1, wg2, bg2, Q);
    k1_fuse<<<2048, 256, 0, stream>>>(nodes, hu, hr, hm, sa, smk,
                                      features, r_embed, Q, comb, 2048 * 4);
    k2_gemm<<<BB / 32, 256, 0, stream>>>(comb, w1, b1, out);
}

// Round 2
// 146.376 us; speedup vs baseline: 1.1118x; 1.1118x over previous
//
#include <hip/hip_runtime.h>
#include <cstdint>
#include <cstddef>

#define NUSERS 100000
#define BB 16384

static __device__ __forceinline__ float readlane_f(float v, int l) {
    return __uint_as_float(__builtin_amdgcn_readlane(__float_as_uint(v), l));
}
static __device__ __forceinline__ int readlane_i(int v, int l) {
    return __builtin_amdgcn_readlane(v, l);
}

// ---------------- K0: per-user attention score Q[u] = tanh(f[u]@wg1+bg1)@wg2 + bg2
__global__ __launch_bounds__(256) void k0_scores(
    const float* __restrict__ features, const float* __restrict__ wg1,
    const float* __restrict__ bg1, const float* __restrict__ wg2,
    const float* __restrict__ bg2, float* __restrict__ Q)
{
    __shared__ float frow[16 * 68];   // 16 user rows, padded
    __shared__ float wg1t[16 * 68];   // wg1 transposed [k][d], padded
    const int tid = threadIdx.x;
    const int blk = blockIdx.x;
    const float* fbase = features + (size_t)blk * 16 * 64;
    for (int i = tid; i < 1024; i += 256) {
        frow[(i >> 6) * 68 + (i & 63)] = fbase[i];
        wg1t[(i & 15) * 68 + (i >> 4)] = wg1[i];
    }
    __syncthreads();
    const int k = tid & 15, ul = tid >> 4;
    float x = bg1[k];
    #pragma unroll
    for (int d4 = 0; d4 < 16; ++d4) {
        const float4 f = *(const float4*)&frow[ul * 68 + d4 * 4];
        const float4 w = *(const float4*)&wg1t[k * 68 + d4 * 4];
        x += f.x * w.x + f.y * w.y + f.z * w.z + f.w * w.w;
    }
    // tanh via v_exp_f32 (avoids libm tanhf path); x tiny in practice, clamp for safety
    float xx = fminf(fmaxf(x, -9.f), 9.f);
    float e2 = __expf(2.f * xx);
    float th = (e2 - 1.f) / (e2 + 1.f);
    float t = th * wg2[k];
    t += __shfl_xor(t, 1);
    t += __shfl_xor(t, 2);
    t += __shfl_xor(t, 4);
    t += __shfl_xor(t, 8);
    if (k == 0) Q[blk * 16 + ul] = t + bg2[0];
}

// ---------------- K1: fused attention-pool + masked means + final GEMM+ReLU
__global__ __launch_bounds__(512) void k1_fuse(
    const int* __restrict__ nodes, const int* __restrict__ hist_u,
    const int* __restrict__ hist_r, const int* __restrict__ hist_m,
    const int* __restrict__ soc_a, const int* __restrict__ soc_m,
    const float* __restrict__ features, const float* __restrict__ r_embed,
    const float* __restrict__ Q, const float* __restrict__ w1,
    const float* __restrict__ b1p, float* __restrict__ out)
{
    __shared__ float w1s[128 * 64];   // 32 KB
    __shared__ float remb[6 * 64];    // rows 0..4 = r_embed, row 5 = zeros
    __shared__ int hcomp[8][64];      // compacted (u | r<<20) per wave
    __shared__ int scomp[8][32];      // compacted social per wave

    const int tid = threadIdx.x;
    {
        const float4* w14 = (const float4*)w1;
        float4* w1s4 = (float4*)w1s;
        for (int i = tid; i < 2048; i += 512) w1s4[i] = w14[i];
        for (int i = tid; i < 384; i += 512) remb[i] = (i < 320) ? r_embed[i] : 0.f;
    }
    __syncthreads();

    const int lane = tid & 63;
    const int wv = tid >> 6;
    const int e = blockIdx.x * 8 + wv;

    // ---- index loads ----
    int nd = (lane < 8) ? nodes[e * 8 + lane] : 0;
    int hu = 0, hr = 0, hm = 0;
    if (lane < 50) {
        hu = hist_u[e * 50 + lane];
        hr = hist_r[e * 50 + lane];
        hm = hist_m[e * 50 + lane];
    }
    int sa = 0, sk = 0;
    if (lane < 32) {
        sa = soc_a[e * 32 + lane];
        sk = soc_m[e * 32 + lane];
    }

    // ---- rank-compaction of active indices into LDS ----
    uint64_t hb = __ballot(hm != 0);
    const int hc = (int)__popcll(hb);
    int hrank = (int)__popcll(hb & ((1ull << lane) - 1));
    if (hm) hcomp[wv][hrank] = hu | (hr << 20);

    uint64_t sb = __ballot(sk != 0);
    const int scn = (int)__popcll(sb);
    int srank = (int)__popcll(sb & ((1ull << lane) - 1));
    if (sk) scomp[wv][srank] = sa;

    // ---- group attention (Q already holds per-user logits) ----
    float m[8];
    #pragma unroll
    for (int g = 0; g < 8; ++g) {
        int idx = readlane_i(nd, g);
        m[g] = features[idx * 64 + lane];
    }
    float sc = (lane < 8) ? Q[nd] : -1e30f;
    float mx = sc;
    mx = fmaxf(mx, __shfl_xor(mx, 1));
    mx = fmaxf(mx, __shfl_xor(mx, 2));
    mx = fmaxf(mx, __shfl_xor(mx, 4));
    float ex = __expf(sc - mx);
    float sm = ex;
    sm += __shfl_xor(sm, 1);
    sm += __shfl_xor(sm, 2);
    sm += __shfl_xor(sm, 4);
    float al = ex / sm;          // valid on lanes 0..7
    float sf = 0.f;
    #pragma unroll
    for (int g = 0; g < 8; ++g)
        sf += readlane_f(al, g) * m[g];

    // ---- read back compacted lists (lane i holds entry i) ----
    int hpk = hcomp[wv][lane];
    int spk = scomp[wv][lane & 31];

    // ---- history masked mean: 4 independent accumulator chains ----
    float a0 = 0.f, a1 = 0.f, a2 = 0.f, a3 = 0.f;
    int i = 0;
    for (; i + 4 <= hc; i += 4) {
        int p0 = readlane_i(hpk, i);
        int p1 = readlane_i(hpk, i + 1);
        int p2 = readlane_i(hpk, i + 2);
        int p3 = readlane_i(hpk, i + 3);
        a0 += features[(p0 & 0xFFFFF) * 64 + lane] + remb[(p0 >> 20) * 64 + lane];
        a1 += features[(p1 & 0xFFFFF) * 64 + lane] + remb[(p1 >> 20) * 64 + lane];
        a2 += features[(p2 & 0xFFFFF) * 64 + lane] + remb[(p2 >> 20) * 64 + lane];
        a3 += features[(p3 & 0xFFFFF) * 64 + lane] + remb[(p3 >> 20) * 64 + lane];
    }
    for (; i < hc; ++i) {
        int p = readlane_i(hpk, i);
        a0 += features[(p & 0xFFFFF) * 64 + lane] + remb[(p >> 20) * 64 + lane];
    }
    float hmean = ((a0 + a1) + (a2 + a3)) / (float)hc;   // hc >= 1 (mask[:,0]=True)

    // ---- social masked mean: 4 independent accumulator chains ----
    float s0 = 0.f, s1 = 0.f, s2 = 0.f, s3 = 0.f;
    i = 0;
    for (; i + 4 <= scn; i += 4) {
        int q0 = readlane_i(spk, i);
        int q1 = readlane_i(spk, i + 1);
        int q2 = readlane_i(spk, i + 2);
        int q3 = readlane_i(spk, i + 3);
        s0 += features[q0 * 64 + lane];
        s1 += features[q1 * 64 + lane];
        s2 += features[q2 * 64 + lane];
        s3 += features[q3 * 64 + lane];
    }
    for (; i < scn; ++i)
        s0 += features[readlane_i(spk, i) * 64 + lane];
    float smean = ((s0 + s1) + (s2 + s3)) / (float)scn;  // scn >= 1

    float nb = 0.5f * (hmean + smean);

    // ---- fused GEMM epilogue: out[e][n] = relu(b1 + sum_k comb[k]*w1[k][n]) ----
    float acc = b1p[lane];
    #pragma unroll
    for (int k = 0; k < 64; ++k)
        acc += readlane_f(sf, k) * w1s[k * 64 + lane];
    #pragma unroll
    for (int k = 0; k < 64; ++k)
        acc += readlane_f(nb, k) * w1s[(64 + k) * 64 + lane];
    out[(size_t)e * 64 + lane] = fmaxf(acc, 0.f);
}

extern "C" void kernel_launch(void* const* d_in, const int* in_sizes, int n_in,
                              void* d_out, int out_size, void* d_ws, size_t ws_size,
                              hipStream_t stream)
{
    const int*   nodes    = (const int*)d_in[0];
    const int*   hu       = (const int*)d_in[1];
    const int*   hr       = (const int*)d_in[2];
    const int*   hm       = (const int*)d_in[3];
    const int*   sa       = (const int*)d_in[4];
    const int*   smk      = (const int*)d_in[5];
    const float* features = (const float*)d_in[6];
    const float* r_embed  = (const float*)d_in[7];
    const float* wg1      = (const float*)d_in[8];
    const float* bg1      = (const float*)d_in[9];
    const float* wg2      = (const float*)d_in[10];
    const float* bg2      = (const float*)d_in[11];
    const float* w1       = (const float*)d_in[12];
    const float* b1       = (const float*)d_in[13];
    float* out = (float*)d_out;

    float* Q = (float*)d_ws;   // 100000 floats

    k0_scores<<<NUSERS / 16, 256, 0, stream>>>(features, wg1, bg1, wg2, bg2, Q);
    k1_fuse<<<BB / 8, 512, 0, stream>>>(nodes, hu, hr, hm, sa, smk,
                                        features, r_embed, Q, w1, b1, out);
}